// Round 6
// baseline (209.579 us; speedup 1.0000x reference)
//
#include <hip/hip_runtime.h>

#define BB 256
#define TT 256
#define CC 512
#define HH 64

typedef __bf16 bf16;
typedef __bf16 bf16x4 __attribute__((ext_vector_type(4)));
typedef __bf16 bf16x8 __attribute__((ext_vector_type(8)));
typedef float  f32x4  __attribute__((ext_vector_type(4)));

#define MFMA16(a, b, c) __builtin_amdgcn_mfma_f32_16x16x32_bf16((a), (b), (c), 0, 0, 0)

typedef __attribute__((address_space(1))) const void cas1_void;
typedef __attribute__((address_space(3))) void as3_void;
// Fire-and-forget global->LDS DMA, 16 B/lane. LDS dest = wave-uniform base + lane*16.
__device__ __forceinline__ void g2lds16(const void* g, void* l) {
    __builtin_amdgcn_global_load_lds((cas1_void*)g, (as3_void*)l, 16, 0, 0);
}

// ---------------------------------------------------------------------------
// K0: transpose fp32 weights into bf16 wt[n][k] (n = 0..191 spanning q,k,v).
// ---------------------------------------------------------------------------
__global__ __launch_bounds__(256) void wtrans(const float* __restrict__ Wk,
                                              const float* __restrict__ Wq,
                                              const float* __restrict__ Wv,
                                              bf16* __restrict__ wt) {
    int which = blockIdx.y;
    const float* W = (which == 0) ? Wq : (which == 1) ? Wk : Wv;
    int idx = blockIdx.x * 256 + threadIdx.x;   // 0..8191
    int n = idx & 63, k4 = idx >> 6;            // k4: 0..127
    bf16x4 o;
    #pragma unroll
    for (int i = 0; i < 4; ++i) o[i] = (bf16)W[(k4 * 4 + i) * HH + n];
    *(bf16x4*)(&wt[which * (CC * HH) + n * CC + k4 * 4]) = o;
}

// ---------------------------------------------------------------------------
// K1: FULLY FUSED qkv+attention, 1024 thr (16 waves = 4 waves/SIMD), grid
// 256, 1 block/CU. GEMM K-loop is NOW a counted-vmcnt pipeline (T3+T4):
// 3 LDS buffers, stage slab kc+1 before compute kc, then
// s_waitcnt vmcnt(3|2) + RAW s_barrier -- waits only slab kc, leaving slab
// kc+1's DMAs in flight ACROSS the barrier (the old __syncthreads drained
// vmcnt(0), emptying the HBM queue every step = the m218 drain0 trap).
// Race audit: buffer staged in iter kc was last read in compute(kc-2),
// strictly before iter kc-1's block-wide barrier; per-wave vmcnt guards own
// DMAs, barrier publishes block-wide.
// Epilogue writes q/k/v into swizzled LDS; attn phase: one 16-row tile per
// wave, SIMD-balanced bijection, online flash softmax in 4 quarter-passes.
// LDS map (132 KB): x bufs 3x32K [0,96K); wt bufs 3x12K [96K,132K) -- all
// die before attn overlays qs[0,32K) ks[32K,64K) vs[64K,96K) pbuf[96K,128K).
// ---------------------------------------------------------------------------
__global__ __launch_bounds__(1024) void fused(const float* __restrict__ x,
                                              const bf16* __restrict__ wt,
                                              float* __restrict__ out) {
    __shared__ __align__(16) char smem[135168];
    const int tid  = threadIdx.x;
    const int wv   = tid >> 6;          // 0..15
    const int lane = tid & 63;
    const int quad = lane >> 4;
    const int l15  = lane & 15;
    const int l7   = l15 & 7;
    const int l3   = l15 & 3;
    const int b    = blockIdx.x;
    const float* xg = x + (size_t)b * TT * CC;

    // ---- stage one BK=32 slab into buffer p: x[256][32] + wt[192][32] ----
    // per wave: 2 x-DMAs (all waves) + 1 wt-DMA (waves 0..11)
    auto stage = [&](int p, int kc) {
        char* xbase = smem + p * 32768;
        #pragma unroll
        for (int j = 0; j < 2; ++j) {
            int s = j * 1024 + tid;         // slot 0..2047
            int r = s >> 3, up = s & 7;
            int u = up ^ (r & 7);           // global 16B-unit for this slot
            const float* gp = xg + (size_t)r * CC + kc * 32 + u * 4;
            g2lds16(gp, xbase + (j * 1024 + wv * 64) * 16);
        }
        if (wv < 12) {                      // wave-uniform: 12 waves x 16 n-rows
            char* wbase = smem + 98304 + p * 12288;
            int n = wv * 16 + (lane >> 2);
            int u = (lane & 3) ^ (n & 3);
            const bf16* gp = wt + (size_t)n * CC + kc * 32 + u * 8;
            g2lds16(gp, wbase + wv * 1024);
        }
    };

    f32x4 acc[12];
    #pragma unroll
    for (int nt = 0; nt < 12; ++nt) acc[nt] = (f32x4){0.f, 0.f, 0.f, 0.f};

    stage(0, 0);                            // slab 0 in flight (3|2 per wave)
    int pc = 0;
    for (int kc = 0; kc < 16; ++kc) {
        int pn = (pc == 2) ? 0 : pc + 1;
        if (kc < 15) {
            stage(pn, kc + 1);              // prefetch: stays in flight across barrier
            if (wv < 12) asm volatile("s_waitcnt vmcnt(3)" ::: "memory");
            else         asm volatile("s_waitcnt vmcnt(2)" ::: "memory");
        } else {
            asm volatile("s_waitcnt vmcnt(0)" ::: "memory");
        }
        __builtin_amdgcn_s_barrier();       // slab kc published block-wide

        const char* xbase = smem + pc * 32768;
        const char* wbase = smem + 98304 + pc * 12288;
        int row = wv * 16 + l15;
        const char* rp = xbase + row * 128;
        f32x4 x0 = *(const f32x4*)(rp + (((quad * 2)     ^ l7) * 16));
        f32x4 x1 = *(const f32x4*)(rp + (((quad * 2 + 1) ^ l7) * 16));
        bf16x8 a0;
        #pragma unroll
        for (int j = 0; j < 4; ++j) {
            a0[j] = (bf16)x0[j]; a0[j + 4] = (bf16)x1[j];
        }
        #pragma unroll
        for (int nt = 0; nt < 12; ++nt) {
            int n = (nt >> 2) * 64 + (nt & 3) * 16 + l15;   // n&3 == l3
            const char* np = wbase + n * 64;
            bf16x8 b0 = *(const bf16x8*)(np + ((quad ^ l3) * 16));
            acc[nt] = MFMA16(a0, b0, acc[nt]);
        }
        pc = pn;
    }
    __syncthreads();                        // all compute(15) readers done

    // ---- epilogue: q/k/v accs -> swizzled LDS (staging bytes now dead) ----
    bf16* qs = (bf16*)smem;                 // [256 rows][64 h], u^(r&7)
    bf16* ks = (bf16*)(smem + 32768);       // same layout
    bf16* vs = (bf16*)(smem + 65536);       // v^T [64 h][256 t], u^(h&31)
    const float scale = 0.044194173824159216f;  // 512^-0.5, folded into q
    {
        int gt = wv * 16 + quad * 4;
        #pragma unroll
        for (int nt = 0; nt < 12; ++nt) {
            int h = (nt & 3) * 16 + l15;
            int wch = nt >> 2;
            if (wch == 0) {
                #pragma unroll
                for (int r = 0; r < 4; ++r) {
                    int row = gt + r;
                    *(bf16*)((char*)qs + row * 128 + (((h >> 3) ^ (row & 7)) * 16)
                             + (h & 7) * 2) = (bf16)(acc[nt][r] * scale);
                }
            } else if (wch == 1) {
                #pragma unroll
                for (int r = 0; r < 4; ++r) {
                    int row = gt + r;
                    *(bf16*)((char*)ks + row * 128 + (((h >> 3) ^ (row & 7)) * 16)
                             + (h & 7) * 2) = (bf16)(acc[nt][r]);
                }
            } else {
                bf16x4 pv;
                #pragma unroll
                for (int r = 0; r < 4; ++r) pv[r] = (bf16)(acc[nt][r]);
                *(bf16x4*)((char*)vs + h * 512 + (((gt >> 3) ^ (h & 31)) * 16)
                           + ((gt >> 2) & 1) * 8) = pv;
            }
        }
    }
    __syncthreads();                        // q/k/v visible to all waves

    // ---- attention: one tile per wave, SIMD-balanced bijection ----
    bf16* pb = (bf16*)(smem + 98304 + wv * 2048);   // [16 rows][64 k] quarter
    const int w0 = wv & 1, w1 = (wv >> 1) & 1, w2 = (wv >> 2) & 1, w3 = wv >> 3;
    const int rt = (w3 << 3) | ((w1 ^ w3) << 2) | (w2 << 1) | (w0 ^ w2);
    const int rowbase = rt * 16;
    const int ctmax = rt;
    const int t = rowbase + l15;

    // Q B-frags from LDS
    const char* qp = (const char*)qs + t * 128;
    bf16x8 bq0 = *(const bf16x8*)(qp + ((quad ^ l7) * 16));
    bf16x8 bq1 = *(const bf16x8*)(qp + (((4 + quad) ^ l7) * 16));

    float m_run = -3.0e38f, sm = 0.f;
    f32x4 o[4];
    #pragma unroll
    for (int ht = 0; ht < 4; ++ht) o[ht] = (f32x4){0.f, 0.f, 0.f, 0.f};

    #pragma unroll
    for (int qp4 = 0; qp4 < 4; ++qp4) {
        if (qp4 * 4 <= ctmax) {             // wave-uniform
            // QK^T for this quarter (cts qp4*4 .. +3)
            f32x4 sv[4];
            #pragma unroll
            for (int c2 = 0; c2 < 4; ++c2) {
                int ct = qp4 * 4 + c2;
                if (ct <= ctmax) {          // wave-uniform
                    const char* kp = (const char*)ks + (ct * 16 + l15) * 128;
                    bf16x8 k0 = *(const bf16x8*)(kp + ((quad ^ l7) * 16));
                    bf16x8 k1 = *(const bf16x8*)(kp + (((4 + quad) ^ l7) * 16));
                    f32x4 a = (f32x4){0.f, 0.f, 0.f, 0.f};
                    a = MFMA16(k0, bq0, a);
                    a = MFMA16(k1, bq1, a);
                    #pragma unroll
                    for (int r = 0; r < 4; ++r) {
                        int s = ct * 16 + quad * 4 + r;
                        sv[c2][r] = (s <= t) ? a[r] : -3.0e38f;
                    }
                }
            }
            // quarter max + online rescale (exact flash combine)
            float mq = -3.0e38f;
            #pragma unroll
            for (int c2 = 0; c2 < 4; ++c2)
                if (qp4 * 4 + c2 <= ctmax) {
                    #pragma unroll
                    for (int r = 0; r < 4; ++r) mq = fmaxf(mq, sv[c2][r]);
                }
            mq = fmaxf(mq, __shfl_xor(mq, 16));
            mq = fmaxf(mq, __shfl_xor(mq, 32));
            float mnew = fmaxf(m_run, mq);
            float alpha = __expf(m_run - mnew);     // first pass: exp(-inf)=0
            sm *= alpha;
            #pragma unroll
            for (int ht = 0; ht < 4; ++ht)
                #pragma unroll
                for (int r = 0; r < 4; ++r) o[ht][r] *= alpha;
            m_run = mnew;

            // exp + P^T quarter into wave-private pbuf
            #pragma unroll
            for (int c2 = 0; c2 < 4; ++c2) {
                int ct = qp4 * 4 + c2;
                if (ct <= ctmax) {
                    bf16x4 ev;
                    #pragma unroll
                    for (int r = 0; r < 4; ++r) {
                        float e = __expf(sv[c2][r] - m_run);
                        sm += e;
                        ev[r] = (bf16)e;
                    }
                    int u = 2 * c2 + (quad >> 1);
                    *(bf16x4*)((char*)pb + l15 * 128 + ((u ^ l7) * 16)
                               + (quad & 1) * 8) = ev;
                }
            }
            if (ctmax >= qp4 * 4 && ctmax < qp4 * 4 + 4 && !(ctmax & 1)) {
                int c2z = (ctmax & 3) + 1;  // zero dead half of last 32-chunk
                int u = 2 * c2z + (quad >> 1);
                *(bf16x4*)((char*)pb + l15 * 128 + ((u ^ l7) * 16)
                           + (quad & 1) * 8) =
                    (bf16x4){(bf16)0.f, (bf16)0.f, (bf16)0.f, (bf16)0.f};
            }
            asm volatile("" ::: "memory");  // keep ds_reads after ds_writes

            // PV for this quarter (ks2 = qp4*2 .. +1)
            #pragma unroll
            for (int k2 = 0; k2 < 2; ++k2) {
                int ks2 = qp4 * 2 + k2;
                if (ks2 <= (ctmax >> 1)) {  // wave-uniform
                    int ur = 4 * k2 + quad;
                    bf16x8 pf = *(const bf16x8*)((char*)pb + l15 * 128
                                                 + ((ur ^ l7) * 16));
                    #pragma unroll
                    for (int ht = 0; ht < 4; ++ht) {
                        int vr = ht * 16 + l15;
                        bf16x8 vf = *(const bf16x8*)((const char*)vs + vr * 512
                                     + (((ks2 * 4 + quad) ^ (vr & 31)) * 16));
                        o[ht] = MFMA16(vf, pf, o[ht]);
                    }
                }
            }
            asm volatile("" ::: "memory");  // pbuf reuse next quarter
        }
    }
    sm += __shfl_xor(sm, 16);
    sm += __shfl_xor(sm, 32);

    // Epilogue: normalize + packed fp32 stores (O^T: col=l15=qrow)
    float rinv = 1.0f / sm;
    #pragma unroll
    for (int ht = 0; ht < 4; ++ht) {
        f32x4 ov;
        #pragma unroll
        for (int r = 0; r < 4; ++r) ov[r] = o[ht][r] * rinv;
        *(f32x4*)(&out[((size_t)b * TT + t) * HH + ht * 16 + quad * 4]) = ov;
    }
}

// ---------------------------------------------------------------------------
extern "C" void kernel_launch(void* const* d_in, const int* in_sizes, int n_in,
                              void* d_out, int out_size, void* d_ws, size_t ws_size,
                              hipStream_t stream) {
    const float* x  = (const float*)d_in[0];
    const float* Wk = (const float*)d_in[1];
    const float* Wq = (const float*)d_in[2];
    const float* Wv = (const float*)d_in[3];

    bf16* wt = (bf16*)d_ws;                          // 3 * 512*64 elems
    float* out = (float*)d_out;

    wtrans<<<dim3(32, 3), 256, 0, stream>>>(Wk, Wq, Wv, wt);
    fused<<<dim3(256), 1024, 0, stream>>>(x, wt, out);
}